// Round 1
// baseline (155.083 us; speedup 1.0000x reference)
//
#include <hip/hip_runtime.h>
#include <math.h>

#define KQ   32768
#define CC   100
#define BB   1024
#define DD   128
#define NTOT (BB + KQ)        // 33792
#define CB_CENT 1056
#define NCB  1060             // 32-row blocks in X2
#define NHIST 33              // histogram partial blocks
#define NCG2 132              // branch-2 col groups (8 cb each)
#define CG_SUP 141            // sup group id (after 9 branch-1 groups)
#define NSL  141              // partial-sum slices (132 b2 + 9 b1)
#define NCI  18               // ci range for gemm grid (8*32*18 = 4608 blocks)

#define INV_T  14.285714285714286f
#define K2E    20.609929f     // INV_T * log2(e)
#define ALPHA  0.05f
#define EPSV   1e-12f

typedef __attribute__((ext_vector_type(8)))  short          short8;
typedef __attribute__((ext_vector_type(8)))  unsigned short ushort8;
typedef __attribute__((ext_vector_type(16))) float          float16;

__device__ __forceinline__ unsigned short f2bf_rne(float f) {
    unsigned int u = __float_as_uint(f);
    return (unsigned short)((u + 0x7FFFu + ((u >> 16) & 1u)) >> 16);
}

// X2 layout per 32-row block cb (8192 B): [ks 0..7][lane 0..63][16 B]
// element (row r, k): cb=r>>5, ks=k>>4, lane=(r&31)+32*((k>>3)&1), j=k&7
// == 32x32x16 MFMA A/B operand layout (verified R2-R15).
// HARD RULES: no device-scope fences/tickets in hot kernel (R13);
// never plain-store into a cross-block atomic accumulation target (R14).

// ---------------- prep: convert+tile (1 cb/block) + partial histograms ----------------
__global__ __launch_bounds__(256) void prep_k(const float* __restrict__ feats,
                                              const float* __restrict__ centers,
                                              const int* __restrict__ labels,
                                              unsigned short* __restrict__ X2,
                                              int* __restrict__ cntP,
                                              int* __restrict__ cntB) {
    const int b = blockIdx.x, t = threadIdx.x;
    if (b >= NCB) {  // histogram partials: each block owns its own 128-int slice
        const int h = b - NCB;
        __shared__ int hA[CC], hB[CC];
        if (t < CC) { hA[t] = 0; hB[t] = 0; }
        __syncthreads();
        const int base = h * 1024;
#pragma unroll
        for (int q = 0; q < 4; ++q) {
            int l = labels[base + q * 256 + t];
            atomicAdd(&hA[l], 1);
            if (h == 0) atomicAdd(&hB[l], 1);   // batch rows are exactly block 0's range
        }
        __syncthreads();
        if (t < 128) {
            cntP[h * 128 + t] = (t < CC) ? hA[t] : 0;
            if (h == 0) cntB[t] = (t < CC) ? hB[t] : 0;
        }
        return;
    }
    __shared__ unsigned short sm[8 * 66 * 8];   // stride-66 slots
    const int cb = b;
    const int rl = t >> 3, c8 = t & 7;
    const int r = cb * 32 + rl;
    const float* src;
    if (r < NTOT)            src = &feats[(size_t)r * DD];
    else if (r < NTOT + CC)  src = &centers[(size_t)(r - NTOT) * DD];
    else                     src = nullptr;
#pragma unroll
    for (int s = 0; s < 2; ++s) {
        const int c8p = c8 + 8 * s;
        float v[8];
        if (src) {
            const float4* p = (const float4*)(src + c8p * 8);
            float4 q0 = p[0], q1 = p[1];
            v[0]=q0.x; v[1]=q0.y; v[2]=q0.z; v[3]=q0.w;
            v[4]=q1.x; v[5]=q1.y; v[6]=q1.z; v[7]=q1.w;
        } else {
#pragma unroll
            for (int j = 0; j < 8; ++j) v[j] = 0.f;
        }
        ushort8 H;
#pragma unroll
        for (int m = 0; m < 8; ++m) H[m] = f2bf_rne(v[m]);
        const int ks = c8p >> 1, lh = c8p & 1;
        *(ushort8*)&sm[(ks * 66 + rl + 32 * lh) * 8] = H;
    }
    __syncthreads();
    ushort8* dst = (ushort8*)((char*)X2 + (size_t)cb * 8192);
#pragma unroll
    for (int j = 0; j < 2; ++j) {
        const int idx = j * 256 + t;
        const int ks = idx >> 6, ln2 = idx & 63;
        dst[idx] = *(const ushort8*)&sm[(ks * 66 + ln2) * 8];
    }
}

// ---------------- tables: one tiny block; sums hist partials, emits weight tables ------
__global__ __launch_bounds__(128) void tables_k(
    const int* __restrict__ cntP, const int* __restrict__ cntB,
    float2* __restrict__ wA, float2* __restrict__ w1, float2* __restrict__ wS,
    float* __restrict__ cAf, int* __restrict__ cBi) {
    const int t = threadIdx.x;   // 0..127
    int s = 0;
#pragma unroll
    for (int h = 0; h < NHIST; ++h) s += cntP[h * 128 + t];
    float cf = (float)s;
    float rn = (s > 0) ? __builtin_amdgcn_rcpf(cf) : 0.f;
    float dr = (s > 0) ? (__builtin_amdgcn_rcpf(cf - ALPHA) - rn) : 0.f;
    wA[t] = make_float2(rn, dr);
    wS[t] = make_float2(__builtin_amdgcn_rcpf(cf),
                        __builtin_amdgcn_rcpf(fmaxf(cf - 1.f, 1.f)));
    int sb = cntB[t];
    float c1 = (float)(sb + 1);
    float r1 = __builtin_amdgcn_rcpf(c1);
    w1[t] = make_float2(r1, __builtin_amdgcn_rcpf(fmaxf(c1 - 1.f, 1.f)) - r1);
    cAf[t] = cf;
    cBi[t] = sb;
}

// ---------------- epilogue for one 32x32 tile ----------------
__device__ __forceinline__ void epi_tile(
    const float16& acc, int cb, int lc, float rn, float drm, bool checkDiag,
    int half, int ln, int growbase, const int* rlab, float* sS, float* sN)
{
    const int ccol = cb * 32 + ln;
#pragma unroll
    for (int reg = 0; reg < 16; ++reg) {
        int ro = (reg & 3) + 8 * (reg >> 2) + 4 * half;
        float a  = acc[reg];
        float mf = (lc == rlab[reg]) ? 1.f : 0.f;
        float wgt = fmaf(mf, drm, rn);
        if (checkDiag) {                 // wave-uniform
            bool d = (ccol == growbase + ro);
            wgt = d ? 0.f : wgt;
            mf  = d ? 0.f : mf;
        }
        float e = exp2f(fmaf(a, K2E, -K2E));
        sS[reg] = fmaf(e, wgt, sS[reg]);
        sN[reg] = fmaf(mf, a, sN[reg]);  // un-scaled dot; *INV_T at finalize
    }
}

// ---------------- dual-stream pair of 32x32 tiles ----------------
__device__ __forceinline__ void pair_tiles(
    const char* Xb, int cb0, int cb1,
    int lc0, float rn0, float drm0, bool dg0,
    int lc1, float rn1, float drm1, bool dg1,
    int lane, int half, int ln, int growbase,
    const short8* Ah, const int* rlab, float* sS, float* sN)
{
    const size_t b0 = (size_t)cb0 * 8192 + (size_t)lane * 16;
    const size_t b1 = (size_t)cb1 * 8192 + (size_t)lane * 16;
    float16 a0, a1;
#pragma unroll
    for (int reg = 0; reg < 16; ++reg) { a0[reg] = 0.f; a1[reg] = 0.f; }
#pragma unroll
    for (int ks = 0; ks < 8; ++ks) {
        short8 B0 = *(const short8*)(Xb + b0 + (size_t)ks * 1024);
        short8 B1 = *(const short8*)(Xb + b1 + (size_t)ks * 1024);
        a0 = __builtin_amdgcn_mfma_f32_32x32x16_bf16(Ah[ks], B0, a0, 0, 0, 0);
        a1 = __builtin_amdgcn_mfma_f32_32x32x16_bf16(Ah[ks], B1, a1, 0, 0, 0);
    }
    epi_tile(a0, cb0, lc0, rn0, drm0, dg0, half, ln, growbase, rlab, sS, sN);
    epi_tile(a1, cb1, lc1, rn1, drm1, dg1, half, ln, growbase, rlab, sS, sN);
}

// ---------------- fused GEMM (b2 + b1) + sup-sums; single-wave blocks, no LDS ----------
// grid 4608 = 8 xcd * 32 rb * 18 ci; cg = xcd + 8*ci (same-cg blocks share an XCD's L2).
// cg<132: branch2 (8 cb). 132..140: branch1 (4 cb). 141: sup sums. >141: idle.
__global__ __launch_bounds__(64, 4) void gemm_k(
    const unsigned short* __restrict__ X2, const int* __restrict__ labels,
    const float2* __restrict__ wA, const float2* __restrict__ w1,
    const float2* __restrict__ wS, const float* __restrict__ sup,
    float* __restrict__ pS, float* __restrict__ pN,
    float* __restrict__ supS, float* __restrict__ supLi) {
    const int b = blockIdx.x;
    const int xcd = b & 7, u = b >> 3;       // u 0..575
    const int ci = u >> 5, rb = u & 31;      // ci 0..17
    const int cg = xcd + 8 * ci;
    if (cg > CG_SUP) return;

    const int lane = threadIdx.x & 63;
    const int half = lane >> 5, ln = lane & 31;
    const char* Xb = (const char*)X2;

    if (cg == CG_SUP) {  // sup-logits exp-sums: this wave owns rows rb*32..rb*32+31
        const int c0 = lane, c1 = lane + 64;
        float2 t0 = wS[c0];
        float rA0 = t0.x, rAm0 = t0.y;
        float rA1 = 0.f, rAm1 = 0.f;
        if (lane < 36) { float2 t1 = wS[c1]; rA1 = t1.x; rAm1 = t1.y; }
        for (int rr = 0; rr < 32; ++rr) {
            int row = rb * 32 + rr;
            int li = labels[row];
            const float* srow = &sup[(size_t)row * CC];
            float v0 = srow[c0];
            float s = __expf(v0 - INV_T) * ((c0 == li) ? rAm0 : rA0);
            float liv = (c0 == li) ? v0 : 0.f;
            if (lane < 36) {
                float v1 = srow[c1];
                s += __expf(v1 - INV_T) * ((c1 == li) ? rAm1 : rA1);
                liv += (c1 == li) ? v1 : 0.f;
            }
#pragma unroll
            for (int off = 1; off < 64; off <<= 1) {
                s += __shfl_xor(s, off, 64);
                liv += __shfl_xor(liv, off, 64);
            }
            if (lane == 0) { supS[row] = s; supLi[row] = liv; }
        }
        return;
    }

    const int growbase = rb * 32;
    short8 Ah[8];
    {
        size_t abase = (size_t)rb * 8192 + (size_t)lane * 16;
#pragma unroll
        for (int ks = 0; ks < 8; ++ks)
            Ah[ks] = *(const short8*)(Xb + abase + (size_t)ks * 1024);
    }
    int rlab[16];
#pragma unroll
    for (int reg = 0; reg < 16; ++reg) {
        int ro = (reg & 3) + 8 * (reg >> 2) + 4 * half;
        rlab[reg] = labels[growbase + ro];
    }
    float sS[16], sN[16];
#pragma unroll
    for (int reg = 0; reg < 16; ++reg) { sS[reg] = 0.f; sN[reg] = 0.f; }

    const bool isB2 = (cg < NCG2);
    const int t1 = cg - NCG2;
    if (isB2) {
#pragma unroll
        for (int p = 0; p < 4; ++p) {
            const int cb0 = cg * 8 + 2 * p, cb1 = cb0 + 1;
            int lc0 = labels[cb0 * 32 + ln];
            int lc1 = labels[cb1 * 32 + ln];
            float2 wv0 = wA[lc0], wv1 = wA[lc1];
            pair_tiles(Xb, cb0, cb1, lc0, wv0.x, wv0.y, cb0 == rb,
                       lc1, wv1.x, wv1.y, cb1 == rb,
                       lane, half, ln, growbase, Ah, rlab, sS, sN);
        }
    } else {
        const bool isBatch = (t1 < 8);
#pragma unroll
        for (int p = 0; p < 2; ++p) {
            int cb0, cb1, lc0, lc1;
            if (isBatch) {
                cb0 = t1 * 4 + 2 * p; cb1 = cb0 + 1;
                lc0 = labels[cb0 * 32 + ln];
                lc1 = labels[cb1 * 32 + ln];
            } else {
                cb0 = CB_CENT + 2 * p; cb1 = cb0 + 1;
                int q0 = cb0 * 32 + ln - NTOT, q1 = cb1 * 32 + ln - NTOT;
                lc0 = (q0 < CC) ? q0 : -1;
                lc1 = (q1 < CC) ? q1 : -1;
            }
            float2 wv0 = w1[(lc0 >= 0) ? lc0 : 0];
            float2 wv1 = w1[(lc1 >= 0) ? lc1 : 0];
            float rn0  = (lc0 >= 0) ? wv0.x : 0.f;
            float drm0 = (lc0 >= 0) ? wv0.y : 0.f;
            float rn1v  = (lc1 >= 0) ? wv1.x : 0.f;
            float drm1v = (lc1 >= 0) ? wv1.y : 0.f;
            pair_tiles(Xb, cb0, cb1, lc0, rn0, drm0, isBatch && (cb0 == rb),
                       lc1, rn1v, drm1v, isBatch && (cb1 == rb),
                       lane, half, ln, growbase, Ah, rlab, sS, sN);
        }
    }
    const int slice = isB2 ? cg : (NCG2 + t1);
#pragma unroll
    for (int reg = 0; reg < 16; ++reg) {
        float a = sS[reg], c = sN[reg];
#pragma unroll
        for (int off = 1; off < 32; off <<= 1) {
            a += __shfl_xor(a, off, 64);
            c += __shfl_xor(c, off, 64);
        }
        if (ln == 0) {
            int ro = (reg & 3) + 8 * (reg >> 2) + 4 * half;
            int grow = growbase + ro;
            pS[(size_t)slice * BB + grow] = a;
            pN[(size_t)slice * BB + grow] = c;
        }
    }
}

// ---------------- finalize: one block, 1024 threads, plain store (no memset needed) ----
__global__ __launch_bounds__(1024) void finalize_k(
    const int* __restrict__ labels,
    const float* __restrict__ cAf, const int* __restrict__ cBi,
    const float* __restrict__ pS, const float* __restrict__ pN,
    const float* __restrict__ supS, const float* __restrict__ supLi,
    float* __restrict__ out) {
    const int t = threadIdx.x;
    __shared__ float cA_s[128];
    __shared__ int   cB_s[128];
    if (t < 128) { cA_s[t] = cAf[t]; cB_s[t] = cBi[t]; }
    __syncthreads();
    const int li = labels[t];
    float S2 = supS[t], N2 = 0.f;
#pragma unroll 4
    for (int c = 0; c < NCG2; ++c) {
        S2 += pS[(size_t)c * BB + t];
        N2 += pN[(size_t)c * BB + t];
    }
    float S1 = 0.f, N1v = 0.f;
#pragma unroll
    for (int c = NCG2; c < NSL; ++c) {
        S1 += pS[(size_t)c * BB + t];
        N1v += pN[(size_t)c * BB + t];
    }
    N2 *= INV_T; N1v *= INV_T;
    float sli = supLi[t];
    float cA = cA_s[li];
    float msum2 = fmaf(ALPHA, cA - 1.f, 1.f);
    float loss2 = -(fmaf(ALPHA, N2, sli) / msum2 - INV_T - logf(S2 + EPSV));
    float loss1 = -(N1v / (float)cB_s[li] - INV_T - logf(S1 + EPSV));
    float s = loss1 + loss2;
    __shared__ float buf[16];
#pragma unroll
    for (int off = 1; off < 64; off <<= 1) s += __shfl_xor(s, off, 64);
    if ((t & 63) == 0) buf[t >> 6] = s;
    __syncthreads();
    if (t < 64) {
        float x = (t < 16) ? buf[t] : 0.f;
#pragma unroll
        for (int off = 1; off < 16; off <<= 1) x += __shfl_xor(x, off, 64);
        if (t == 0) out[0] = x / (float)BB;   // single writer, plain store
    }
}

extern "C" void kernel_launch(void* const* d_in, const int* in_sizes, int n_in,
                              void* d_out, int out_size, void* d_ws, size_t ws_size,
                              hipStream_t stream) {
    const float* feats   = (const float*)d_in[0];
    const float* sup     = (const float*)d_in[1];
    const float* centers = (const float*)d_in[2];
    const int*   labels  = (const int*)d_in[3];
    float* out = (float*)d_out;
    char*  wsb = (char*)d_ws;

    const size_t X2_BYTES = (size_t)NCB * 8192;         // 8,683,520
    unsigned short* X2 = (unsigned short*)wsb;
    char* base2 = wsb + X2_BYTES;
    int* cntP = (int*)base2;                            // 33*128 ints
    int* cntB = cntP + NHIST * 128;                     // 128 ints
    float2* wA = (float2*)(cntB + 128);                 // 128 float2 (8B-aligned)
    float2* w1 = wA + 128;                              // 128 float2
    float2* wS = w1 + 128;                              // 128 float2
    float*  cAf = (float*)(wS + 128);                   // 128 floats
    int*    cBi = (int*)(cAf + 128);                    // 128 ints
    float* pS = (float*)(cBi + 128);                    // 141*1024
    float* pN = pS + (size_t)NSL * BB;                  // 141*1024
    float* supS  = pN + (size_t)NSL * BB;               // 1024
    float* supLi = supS + BB;                           // 1024

    // 4 nodes; every workspace word written before read (stream-ordered)
    prep_k<<<NCB + NHIST, 256, 0, stream>>>(feats, centers, labels, X2, cntP, cntB);
    tables_k<<<1, 128, 0, stream>>>(cntP, cntB, wA, w1, wS, cAf, cBi);
    gemm_k<<<8 * 32 * NCI, 64, 0, stream>>>(X2, labels, wA, w1, wS, sup,
                                            pS, pN, supS, supLi);
    finalize_k<<<1, 1024, 0, stream>>>(labels, cAf, cBi, pS, pN, supS, supLi, out);
}

// Round 2
// 134.370 us; speedup vs baseline: 1.1541x; 1.1541x over previous
//
#include <hip/hip_runtime.h>
#include <math.h>

#define KQ   32768
#define CC   100
#define BB   1024
#define DD   128
#define NTOT (BB + KQ)        // 33792
#define CB_CENT 1056
#define NCB  1060             // 32-row blocks in X2
#define NHIST 33              // histogram partial blocks
#define NCG2 132              // branch-2 col groups (8 cb each)
#define CG_SUP 141            // sup group id (after 9 branch-1 groups)
#define NSL  141              // partial-sum slices (132 b2 + 9 b1)
#define NCI  18               // ci range for gemm grid (8*32*18 = 4608 blocks)

#define INV_T  14.285714285714286f
#define K2E    20.609929f     // INV_T * log2(e)
#define ALPHA  0.05f
#define EPSV   1e-12f

typedef __attribute__((ext_vector_type(8)))  short          short8;
typedef __attribute__((ext_vector_type(8)))  unsigned short ushort8;
typedef __attribute__((ext_vector_type(16))) float          float16;

__device__ __forceinline__ unsigned short f2bf_rne(float f) {
    unsigned int u = __float_as_uint(f);
    return (unsigned short)((u + 0x7FFFu + ((u >> 16) & 1u)) >> 16);
}

// X2 layout per 32-row block cb (8192 B): [ks 0..7][lane 0..63][16 B]
// element (row r, k): cb=r>>5, ks=k>>4, lane=(r&31)+32*((k>>3)&1), j=k&7
// == 32x32x16 MFMA A/B operand layout (verified R2-R15).
// HARD RULES: no device-scope fences/tickets in hot kernel (R13);
// never plain-store into a cross-block atomic accumulation target (R14);
// gemm_k needs ~112 VGPRs — never bound below 128 (R1 post-mortem: (64,4)
// capped VGPR at 64 -> 126 MB scratch spill traffic, 1.3x regression).

// ---------------- prep: convert+tile (1 cb/block) + partial histograms ----------------
__global__ __launch_bounds__(256) void prep_k(const float* __restrict__ feats,
                                              const float* __restrict__ centers,
                                              const int* __restrict__ labels,
                                              unsigned short* __restrict__ X2,
                                              int* __restrict__ cntP,
                                              int* __restrict__ cntB) {
    const int b = blockIdx.x, t = threadIdx.x;
    if (b >= NCB) {  // histogram partials: each block owns its own 128-int slice
        const int h = b - NCB;
        __shared__ int hA[CC], hB[CC];
        if (t < CC) { hA[t] = 0; hB[t] = 0; }
        __syncthreads();
        const int base = h * 1024;
#pragma unroll
        for (int q = 0; q < 4; ++q) {
            int l = labels[base + q * 256 + t];
            atomicAdd(&hA[l], 1);
            if (h == 0) atomicAdd(&hB[l], 1);   // batch rows are exactly block 0's range
        }
        __syncthreads();
        if (t < 128) {
            cntP[h * 128 + t] = (t < CC) ? hA[t] : 0;
            if (h == 0) cntB[t] = (t < CC) ? hB[t] : 0;
        }
        return;
    }
    __shared__ unsigned short sm[8 * 66 * 8];   // stride-66 slots
    const int cb = b;
    const int rl = t >> 3, c8 = t & 7;
    const int r = cb * 32 + rl;
    const float* src;
    if (r < NTOT)            src = &feats[(size_t)r * DD];
    else if (r < NTOT + CC)  src = &centers[(size_t)(r - NTOT) * DD];
    else                     src = nullptr;
#pragma unroll
    for (int s = 0; s < 2; ++s) {
        const int c8p = c8 + 8 * s;
        float v[8];
        if (src) {
            const float4* p = (const float4*)(src + c8p * 8);
            float4 q0 = p[0], q1 = p[1];
            v[0]=q0.x; v[1]=q0.y; v[2]=q0.z; v[3]=q0.w;
            v[4]=q1.x; v[5]=q1.y; v[6]=q1.z; v[7]=q1.w;
        } else {
#pragma unroll
            for (int j = 0; j < 8; ++j) v[j] = 0.f;
        }
        ushort8 H;
#pragma unroll
        for (int m = 0; m < 8; ++m) H[m] = f2bf_rne(v[m]);
        const int ks = c8p >> 1, lh = c8p & 1;
        *(ushort8*)&sm[(ks * 66 + rl + 32 * lh) * 8] = H;
    }
    __syncthreads();
    ushort8* dst = (ushort8*)((char*)X2 + (size_t)cb * 8192);
#pragma unroll
    for (int j = 0; j < 2; ++j) {
        const int idx = j * 256 + t;
        const int ks = idx >> 6, ln2 = idx & 63;
        dst[idx] = *(const ushort8*)&sm[(ks * 66 + ln2) * 8];
    }
}

// ---------------- tables: one tiny block; sums hist partials, emits weight tables ------
__global__ __launch_bounds__(128) void tables_k(
    const int* __restrict__ cntP, const int* __restrict__ cntB,
    float2* __restrict__ wA, float2* __restrict__ w1, float2* __restrict__ wS,
    float* __restrict__ cAf, int* __restrict__ cBi) {
    const int t = threadIdx.x;   // 0..127
    int s = 0;
#pragma unroll
    for (int h = 0; h < NHIST; ++h) s += cntP[h * 128 + t];
    float cf = (float)s;
    float rn = (s > 0) ? __builtin_amdgcn_rcpf(cf) : 0.f;
    float dr = (s > 0) ? (__builtin_amdgcn_rcpf(cf - ALPHA) - rn) : 0.f;
    wA[t] = make_float2(rn, dr);
    wS[t] = make_float2(__builtin_amdgcn_rcpf(cf),
                        __builtin_amdgcn_rcpf(fmaxf(cf - 1.f, 1.f)));
    int sb = cntB[t];
    float c1 = (float)(sb + 1);
    float r1 = __builtin_amdgcn_rcpf(c1);
    w1[t] = make_float2(r1, __builtin_amdgcn_rcpf(fmaxf(c1 - 1.f, 1.f)) - r1);
    cAf[t] = cf;
    cBi[t] = sb;
}

// ---------------- epilogue for one 32x32 tile ----------------
__device__ __forceinline__ void epi_tile(
    const float16& acc, int cb, int lc, float rn, float drm, bool checkDiag,
    int half, int ln, int growbase, const int* rlab, float* sS, float* sN)
{
    const int ccol = cb * 32 + ln;
#pragma unroll
    for (int reg = 0; reg < 16; ++reg) {
        int ro = (reg & 3) + 8 * (reg >> 2) + 4 * half;
        float a  = acc[reg];
        float mf = (lc == rlab[reg]) ? 1.f : 0.f;
        float wgt = fmaf(mf, drm, rn);
        if (checkDiag) {                 // wave-uniform
            bool d = (ccol == growbase + ro);
            wgt = d ? 0.f : wgt;
            mf  = d ? 0.f : mf;
        }
        float e = exp2f(fmaf(a, K2E, -K2E));
        sS[reg] = fmaf(e, wgt, sS[reg]);
        sN[reg] = fmaf(mf, a, sN[reg]);  // un-scaled dot; *INV_T at finalize
    }
}

// ---------------- dual-stream pair of 32x32 tiles ----------------
__device__ __forceinline__ void pair_tiles(
    const char* Xb, int cb0, int cb1,
    int lc0, float rn0, float drm0, bool dg0,
    int lc1, float rn1, float drm1, bool dg1,
    int lane, int half, int ln, int growbase,
    const short8* Ah, const int* rlab, float* sS, float* sN)
{
    const size_t b0 = (size_t)cb0 * 8192 + (size_t)lane * 16;
    const size_t b1 = (size_t)cb1 * 8192 + (size_t)lane * 16;
    float16 a0, a1;
#pragma unroll
    for (int reg = 0; reg < 16; ++reg) { a0[reg] = 0.f; a1[reg] = 0.f; }
#pragma unroll
    for (int ks = 0; ks < 8; ++ks) {
        short8 B0 = *(const short8*)(Xb + b0 + (size_t)ks * 1024);
        short8 B1 = *(const short8*)(Xb + b1 + (size_t)ks * 1024);
        a0 = __builtin_amdgcn_mfma_f32_32x32x16_bf16(Ah[ks], B0, a0, 0, 0, 0);
        a1 = __builtin_amdgcn_mfma_f32_32x32x16_bf16(Ah[ks], B1, a1, 0, 0, 0);
    }
    epi_tile(a0, cb0, lc0, rn0, drm0, dg0, half, ln, growbase, rlab, sS, sN);
    epi_tile(a1, cb1, lc1, rn1, drm1, dg1, half, ln, growbase, rlab, sS, sN);
}

// ---------------- fused GEMM (b2 + b1) + sup-sums; single-wave blocks, no LDS ----------
// grid 4608 = 8 xcd * 32 rb * 18 ci; cg = xcd + 8*ci (same-cg blocks share an XCD's L2).
// cg<132: branch2 (8 cb). 132..140: branch1 (4 cb). 141: sup sums. >141: idle.
__global__ __launch_bounds__(64, 2) void gemm_k(
    const unsigned short* __restrict__ X2, const int* __restrict__ labels,
    const float2* __restrict__ wA, const float2* __restrict__ w1,
    const float2* __restrict__ wS, const float* __restrict__ sup,
    float* __restrict__ pS, float* __restrict__ pN,
    float* __restrict__ supS, float* __restrict__ supLi) {
    const int b = blockIdx.x;
    const int xcd = b & 7, u = b >> 3;       // u 0..575
    const int ci = u >> 5, rb = u & 31;      // ci 0..17
    const int cg = xcd + 8 * ci;
    if (cg > CG_SUP) return;

    const int lane = threadIdx.x & 63;
    const int half = lane >> 5, ln = lane & 31;
    const char* Xb = (const char*)X2;

    if (cg == CG_SUP) {  // sup-logits exp-sums: this wave owns rows rb*32..rb*32+31
        const int c0 = lane, c1 = lane + 64;
        float2 t0 = wS[c0];
        float rA0 = t0.x, rAm0 = t0.y;
        float rA1 = 0.f, rAm1 = 0.f;
        if (lane < 36) { float2 t1 = wS[c1]; rA1 = t1.x; rAm1 = t1.y; }
        for (int rr = 0; rr < 32; ++rr) {
            int row = rb * 32 + rr;
            int li = labels[row];
            const float* srow = &sup[(size_t)row * CC];
            float v0 = srow[c0];
            float s = __expf(v0 - INV_T) * ((c0 == li) ? rAm0 : rA0);
            float liv = (c0 == li) ? v0 : 0.f;
            if (lane < 36) {
                float v1 = srow[c1];
                s += __expf(v1 - INV_T) * ((c1 == li) ? rAm1 : rA1);
                liv += (c1 == li) ? v1 : 0.f;
            }
#pragma unroll
            for (int off = 1; off < 64; off <<= 1) {
                s += __shfl_xor(s, off, 64);
                liv += __shfl_xor(liv, off, 64);
            }
            if (lane == 0) { supS[row] = s; supLi[row] = liv; }
        }
        return;
    }

    const int growbase = rb * 32;
    short8 Ah[8];
    {
        size_t abase = (size_t)rb * 8192 + (size_t)lane * 16;
#pragma unroll
        for (int ks = 0; ks < 8; ++ks)
            Ah[ks] = *(const short8*)(Xb + abase + (size_t)ks * 1024);
    }
    int rlab[16];
#pragma unroll
    for (int reg = 0; reg < 16; ++reg) {
        int ro = (reg & 3) + 8 * (reg >> 2) + 4 * half;
        rlab[reg] = labels[growbase + ro];
    }
    float sS[16], sN[16];
#pragma unroll
    for (int reg = 0; reg < 16; ++reg) { sS[reg] = 0.f; sN[reg] = 0.f; }

    const bool isB2 = (cg < NCG2);
    const int t1 = cg - NCG2;
    if (isB2) {
#pragma unroll
        for (int p = 0; p < 4; ++p) {
            const int cb0 = cg * 8 + 2 * p, cb1 = cb0 + 1;
            int lc0 = labels[cb0 * 32 + ln];
            int lc1 = labels[cb1 * 32 + ln];
            float2 wv0 = wA[lc0], wv1 = wA[lc1];
            pair_tiles(Xb, cb0, cb1, lc0, wv0.x, wv0.y, cb0 == rb,
                       lc1, wv1.x, wv1.y, cb1 == rb,
                       lane, half, ln, growbase, Ah, rlab, sS, sN);
        }
    } else {
        const bool isBatch = (t1 < 8);
#pragma unroll
        for (int p = 0; p < 2; ++p) {
            int cb0, cb1, lc0, lc1;
            if (isBatch) {
                cb0 = t1 * 4 + 2 * p; cb1 = cb0 + 1;
                lc0 = labels[cb0 * 32 + ln];
                lc1 = labels[cb1 * 32 + ln];
            } else {
                cb0 = CB_CENT + 2 * p; cb1 = cb0 + 1;
                int q0 = cb0 * 32 + ln - NTOT, q1 = cb1 * 32 + ln - NTOT;
                lc0 = (q0 < CC) ? q0 : -1;
                lc1 = (q1 < CC) ? q1 : -1;
            }
            float2 wv0 = w1[(lc0 >= 0) ? lc0 : 0];
            float2 wv1 = w1[(lc1 >= 0) ? lc1 : 0];
            float rn0  = (lc0 >= 0) ? wv0.x : 0.f;
            float drm0 = (lc0 >= 0) ? wv0.y : 0.f;
            float rn1v  = (lc1 >= 0) ? wv1.x : 0.f;
            float drm1v = (lc1 >= 0) ? wv1.y : 0.f;
            pair_tiles(Xb, cb0, cb1, lc0, rn0, drm0, isBatch && (cb0 == rb),
                       lc1, rn1v, drm1v, isBatch && (cb1 == rb),
                       lane, half, ln, growbase, Ah, rlab, sS, sN);
        }
    }
    const int slice = isB2 ? cg : (NCG2 + t1);
#pragma unroll
    for (int reg = 0; reg < 16; ++reg) {
        float a = sS[reg], c = sN[reg];
#pragma unroll
        for (int off = 1; off < 32; off <<= 1) {
            a += __shfl_xor(a, off, 64);
            c += __shfl_xor(c, off, 64);
        }
        if (ln == 0) {
            int ro = (reg & 3) + 8 * (reg >> 2) + 4 * half;
            int grow = growbase + ro;
            pS[(size_t)slice * BB + grow] = a;
            pN[(size_t)slice * BB + grow] = c;
        }
    }
}

// ---------------- finalize: one block, 1024 threads, plain store (no memset needed) ----
__global__ __launch_bounds__(1024) void finalize_k(
    const int* __restrict__ labels,
    const float* __restrict__ cAf, const int* __restrict__ cBi,
    const float* __restrict__ pS, const float* __restrict__ pN,
    const float* __restrict__ supS, const float* __restrict__ supLi,
    float* __restrict__ out) {
    const int t = threadIdx.x;
    __shared__ float cA_s[128];
    __shared__ int   cB_s[128];
    if (t < 128) { cA_s[t] = cAf[t]; cB_s[t] = cBi[t]; }
    __syncthreads();
    const int li = labels[t];
    float S2 = supS[t], N2 = 0.f;
#pragma unroll 4
    for (int c = 0; c < NCG2; ++c) {
        S2 += pS[(size_t)c * BB + t];
        N2 += pN[(size_t)c * BB + t];
    }
    float S1 = 0.f, N1v = 0.f;
#pragma unroll
    for (int c = NCG2; c < NSL; ++c) {
        S1 += pS[(size_t)c * BB + t];
        N1v += pN[(size_t)c * BB + t];
    }
    N2 *= INV_T; N1v *= INV_T;
    float sli = supLi[t];
    float cA = cA_s[li];
    float msum2 = fmaf(ALPHA, cA - 1.f, 1.f);
    float loss2 = -(fmaf(ALPHA, N2, sli) / msum2 - INV_T - logf(S2 + EPSV));
    float loss1 = -(N1v / (float)cB_s[li] - INV_T - logf(S1 + EPSV));
    float s = loss1 + loss2;
    __shared__ float buf[16];
#pragma unroll
    for (int off = 1; off < 64; off <<= 1) s += __shfl_xor(s, off, 64);
    if ((t & 63) == 0) buf[t >> 6] = s;
    __syncthreads();
    if (t < 64) {
        float x = (t < 16) ? buf[t] : 0.f;
#pragma unroll
        for (int off = 1; off < 16; off <<= 1) x += __shfl_xor(x, off, 64);
        if (t == 0) out[0] = x / (float)BB;   // single writer, plain store
    }
}

extern "C" void kernel_launch(void* const* d_in, const int* in_sizes, int n_in,
                              void* d_out, int out_size, void* d_ws, size_t ws_size,
                              hipStream_t stream) {
    const float* feats   = (const float*)d_in[0];
    const float* sup     = (const float*)d_in[1];
    const float* centers = (const float*)d_in[2];
    const int*   labels  = (const int*)d_in[3];
    float* out = (float*)d_out;
    char*  wsb = (char*)d_ws;

    const size_t X2_BYTES = (size_t)NCB * 8192;         // 8,683,520
    unsigned short* X2 = (unsigned short*)wsb;
    char* base2 = wsb + X2_BYTES;
    int* cntP = (int*)base2;                            // 33*128 ints
    int* cntB = cntP + NHIST * 128;                     // 128 ints
    float2* wA = (float2*)(cntB + 128);                 // 128 float2 (8B-aligned)
    float2* w1 = wA + 128;                              // 128 float2
    float2* wS = w1 + 128;                              // 128 float2
    float*  cAf = (float*)(wS + 128);                   // 128 floats
    int*    cBi = (int*)(cAf + 128);                    // 128 ints
    float* pS = (float*)(cBi + 128);                    // 141*1024
    float* pN = pS + (size_t)NSL * BB;                  // 141*1024
    float* supS  = pN + (size_t)NSL * BB;               // 1024
    float* supLi = supS + BB;                           // 1024

    // 4 nodes; every workspace word written before read (stream-ordered)
    prep_k<<<NCB + NHIST, 256, 0, stream>>>(feats, centers, labels, X2, cntP, cntB);
    tables_k<<<1, 128, 0, stream>>>(cntP, cntB, wA, w1, wS, cAf, cBi);
    gemm_k<<<8 * 32 * NCI, 64, 0, stream>>>(X2, labels, wA, w1, wS, sup,
                                            pS, pN, supS, supLi);
    finalize_k<<<1, 1024, 0, stream>>>(labels, cAf, cBi, pS, pN, supS, supLi, out);
}

// Round 3
// 125.939 us; speedup vs baseline: 1.2314x; 1.0669x over previous
//
#include <hip/hip_runtime.h>
#include <math.h>

#define KQ   32768
#define CC   100
#define BB   1024
#define DD   128
#define NTOT (BB + KQ)        // 33792
#define CB_CENT 1056
#define NCB  1060             // 32-row blocks in X2
#define NHIST 33              // histogram partial blocks
#define NCG2 132              // branch-2 col groups (8 cb each)
#define CG_SUP 141            // sup group id (after 9 branch-1 groups)
#define NSL  141              // partial-sum slices (132 b2 + 9 b1)

#define INV_T  14.285714285714286f
#define K2E    20.609929f     // INV_T * log2(e)
#define ALPHA  0.05f
#define EPSV   1e-12f

typedef __attribute__((ext_vector_type(8)))  short          short8;
typedef __attribute__((ext_vector_type(8)))  unsigned short ushort8;
typedef __attribute__((ext_vector_type(16))) float          float16;

__device__ __forceinline__ unsigned short f2bf_rne(float f) {
    unsigned int u = __float_as_uint(f);
    return (unsigned short)((u + 0x7FFFu + ((u >> 16) & 1u)) >> 16);
}

// X2 layout per 32-row block cb (8192 B): [ks 0..7][lane 0..63][16 B]
// element (row r, k): cb=r>>5, ks=k>>4, lane=(r&31)+32*((k>>3)&1), j=k&7
// == 32x32x16 MFMA A/B operand layout (verified R2-R15).
// HARD RULES: no device-scope fences/tickets in hot kernel (R13);
// never plain-store into a cross-block atomic accumulation target (R14);
// gemm_k needs >80 VGPRs — never bound below 128 (R1 post-mortem: (64,4)
// capped VGPR at 64 -> 126 MB scratch spill traffic, 1.3x regression).
// R2 post-mortem: wave-count/TLP changes don't move gemm wall (issue-starved
// per-wave load batches) -> R3 switches to LDS double-buffered staging.

// ---------------- prep: convert+tile (1 cb/block) + partial histograms ----------------
__global__ __launch_bounds__(256) void prep_k(const float* __restrict__ feats,
                                              const float* __restrict__ centers,
                                              const int* __restrict__ labels,
                                              unsigned short* __restrict__ X2,
                                              int* __restrict__ cntP,
                                              int* __restrict__ cntB) {
    const int b = blockIdx.x, t = threadIdx.x;
    if (b >= NCB) {  // histogram partials: each block owns its own 128-int slice
        const int h = b - NCB;
        __shared__ int hA[CC], hB[CC];
        if (t < CC) { hA[t] = 0; hB[t] = 0; }
        __syncthreads();
        const int base = h * 1024;
#pragma unroll
        for (int q = 0; q < 4; ++q) {
            int l = labels[base + q * 256 + t];
            atomicAdd(&hA[l], 1);
            if (h == 0) atomicAdd(&hB[l], 1);   // batch rows are exactly block 0's range
        }
        __syncthreads();
        if (t < 128) {
            cntP[h * 128 + t] = (t < CC) ? hA[t] : 0;
            if (h == 0) cntB[t] = (t < CC) ? hB[t] : 0;
        }
        return;
    }
    __shared__ unsigned short sm[8 * 66 * 8];   // stride-66 slots
    const int cb = b;
    const int rl = t >> 3, c8 = t & 7;
    const int r = cb * 32 + rl;
    const float* src;
    if (r < NTOT)            src = &feats[(size_t)r * DD];
    else if (r < NTOT + CC)  src = &centers[(size_t)(r - NTOT) * DD];
    else                     src = nullptr;
#pragma unroll
    for (int s = 0; s < 2; ++s) {
        const int c8p = c8 + 8 * s;
        float v[8];
        if (src) {
            const float4* p = (const float4*)(src + c8p * 8);
            float4 q0 = p[0], q1 = p[1];
            v[0]=q0.x; v[1]=q0.y; v[2]=q0.z; v[3]=q0.w;
            v[4]=q1.x; v[5]=q1.y; v[6]=q1.z; v[7]=q1.w;
        } else {
#pragma unroll
            for (int j = 0; j < 8; ++j) v[j] = 0.f;
        }
        ushort8 H;
#pragma unroll
        for (int m = 0; m < 8; ++m) H[m] = f2bf_rne(v[m]);
        const int ks = c8p >> 1, lh = c8p & 1;
        *(ushort8*)&sm[(ks * 66 + rl + 32 * lh) * 8] = H;
    }
    __syncthreads();
    ushort8* dst = (ushort8*)((char*)X2 + (size_t)cb * 8192);
#pragma unroll
    for (int j = 0; j < 2; ++j) {
        const int idx = j * 256 + t;
        const int ks = idx >> 6, ln2 = idx & 63;
        dst[idx] = *(const ushort8*)&sm[(ks * 66 + ln2) * 8];
    }
}

// ---------------- tables: one tiny block; sums hist partials, emits weight tables ------
__global__ __launch_bounds__(128) void tables_k(
    const int* __restrict__ cntP, const int* __restrict__ cntB,
    float2* __restrict__ wA, float2* __restrict__ w1, float2* __restrict__ wS,
    float* __restrict__ cAf, int* __restrict__ cBi) {
    const int t = threadIdx.x;   // 0..127
    int s = 0;
#pragma unroll
    for (int h = 0; h < NHIST; ++h) s += cntP[h * 128 + t];
    float cf = (float)s;
    float rn = (s > 0) ? __builtin_amdgcn_rcpf(cf) : 0.f;
    float dr = (s > 0) ? (__builtin_amdgcn_rcpf(cf - ALPHA) - rn) : 0.f;
    wA[t] = make_float2(rn, dr);
    wS[t] = make_float2(__builtin_amdgcn_rcpf(cf),
                        __builtin_amdgcn_rcpf(fmaxf(cf - 1.f, 1.f)));
    int sb = cntB[t];
    float c1 = (float)(sb + 1);
    float r1 = __builtin_amdgcn_rcpf(c1);
    w1[t] = make_float2(r1, __builtin_amdgcn_rcpf(fmaxf(c1 - 1.f, 1.f)) - r1);
    cAf[t] = cf;
    cBi[t] = sb;
}

// ---------------- epilogue for one 32x32 tile ----------------
__device__ __forceinline__ void epi_tile(
    const float16& acc, int cb, int lc, float rn, float drm, bool checkDiag,
    int half, int ln, int growbase, const int* rlab, float* sS, float* sN)
{
    const int ccol = cb * 32 + ln;
#pragma unroll
    for (int reg = 0; reg < 16; ++reg) {
        int ro = (reg & 3) + 8 * (reg >> 2) + 4 * half;
        float a  = acc[reg];
        float mf = (lc == rlab[reg]) ? 1.f : 0.f;
        float wgt = fmaf(mf, drm, rn);
        if (checkDiag) {                 // wave-uniform
            bool d = (ccol == growbase + ro);
            wgt = d ? 0.f : wgt;
            mf  = d ? 0.f : mf;
        }
        float e = exp2f(fmaf(a, K2E, -K2E));
        sS[reg] = fmaf(e, wgt, sS[reg]);
        sN[reg] = fmaf(mf, a, sN[reg]);  // un-scaled dot; *INV_T at finalize
    }
}

// ---------------- fused GEMM (b2 + b1) + sup-sums; 4-wave LDS double-buffer ------------
// grid 1152 = 18 chunk * 8 rgrp * 8 xcd; cg = chunk*8 + xcd (the 8 rgrp blocks of a
// cg share b&7 -> same XCD -> its B tiles stay in that XCD's L2).
// cg<132: branch2 (8 cb). 132..140: branch1 (4 cb). 141: sup sums. 142/143: idle.
// Pipeline: waves co-stage next cb into LDS (reg-staged: 2x16B load early, ds_write
// late) while computing current cb from the other buffer; one barrier per iter.
__global__ __launch_bounds__(256, 2) void gemm_k(
    const unsigned short* __restrict__ X2, const int* __restrict__ labels,
    const float2* __restrict__ wA, const float2* __restrict__ w1,
    const float2* __restrict__ wS, const float* __restrict__ sup,
    float* __restrict__ pS, float* __restrict__ pN,
    float* __restrict__ supS, float* __restrict__ supLi) {
    const int b = blockIdx.x;
    const int xcd = b & 7, rgrp = (b >> 3) & 7, chunk = b >> 6;
    const int cg = chunk * 8 + xcd;
    if (cg > CG_SUP) return;

    const int tid = threadIdx.x;
    const int w = tid >> 6, lane = tid & 63;
    const int half = lane >> 5, ln = lane & 31;
    const int rb = rgrp * 4 + w;
    const char* Xb = (const char*)X2;

    if (cg == CG_SUP) {  // sup-logits exp-sums: wave owns rows rb*32..rb*32+31
        const int c0 = lane, c1 = lane + 64;
        float2 t0 = wS[c0];
        float rA0 = t0.x, rAm0 = t0.y;
        float rA1 = 0.f, rAm1 = 0.f;
        if (lane < 36) { float2 t1v = wS[c1]; rA1 = t1v.x; rAm1 = t1v.y; }
        for (int rr = 0; rr < 32; ++rr) {
            int row = rb * 32 + rr;
            int li = labels[row];
            const float* srow = &sup[(size_t)row * CC];
            float v0 = srow[c0];
            float s = __expf(v0 - INV_T) * ((c0 == li) ? rAm0 : rA0);
            float liv = (c0 == li) ? v0 : 0.f;
            if (lane < 36) {
                float v1 = srow[c1];
                s += __expf(v1 - INV_T) * ((c1 == li) ? rAm1 : rA1);
                liv += (c1 == li) ? v1 : 0.f;
            }
#pragma unroll
            for (int off = 1; off < 64; off <<= 1) {
                s += __shfl_xor(s, off, 64);
                liv += __shfl_xor(liv, off, 64);
            }
            if (lane == 0) { supS[row] = s; supLi[row] = liv; }
        }
        return;
    }

    __shared__ char sm[2 * 8192];   // double-buffered B tile (MFMA operand order)

    const int growbase = rb * 32;
    short8 Ah[8];
    {
        size_t abase = (size_t)rb * 8192 + (size_t)lane * 16;
#pragma unroll
        for (int ks = 0; ks < 8; ++ks)
            Ah[ks] = *(const short8*)(Xb + abase + (size_t)ks * 1024);
    }
    int rlab[16];
#pragma unroll
    for (int reg = 0; reg < 16; ++reg) {
        int ro = (reg & 3) + 8 * (reg >> 2) + 4 * half;
        rlab[reg] = labels[growbase + ro];
    }
    float sS[16], sN[16];
#pragma unroll
    for (int reg = 0; reg < 16; ++reg) { sS[reg] = 0.f; sN[reg] = 0.f; }

    const bool isB2 = (cg < NCG2);
    const int t1 = cg - NCG2;
    const bool isBatch = isB2 || (t1 < 8);
    const int NIT = isB2 ? 8 : 4;
    const int cb0 = isB2 ? cg * 8 : (t1 < 8 ? t1 * 4 : CB_CENT);

    // per-wave staging offsets: wave w owns ks-slices 2w, 2w+1 (1 KB each)
    const int soff = (w * 2) * 1024 + lane * 16;

    // prologue: stage cb0 into buffer 0
    {
        const char* src = Xb + (size_t)cb0 * 8192 + soff;
        short8 s0 = *(const short8*)src;
        short8 s1 = *(const short8*)(src + 1024);
        *(short8*)&sm[soff] = s0;
        *(short8*)&sm[soff + 1024] = s1;
    }
    __syncthreads();

    for (int i = 0; i < NIT; ++i) {
        const int cb = cb0 + i;
        // issue next tile's global loads early (latency hides under compute)
        short8 st0, st1;
        const bool more = (i + 1 < NIT);
        if (more) {
            const char* src = Xb + (size_t)(cb + 1) * 8192 + soff;
            st0 = *(const short8*)src;
            st1 = *(const short8*)(src + 1024);
        }
        // weights for this tile's columns
        int lc; float rn, drm; bool dg;
        if (isBatch) {
            lc = labels[cb * 32 + ln];
            float2 wv = isB2 ? wA[lc] : w1[lc];
            rn = wv.x; drm = wv.y; dg = (cb == rb);
        } else {
            int q = cb * 32 + ln - NTOT;
            lc = (q < CC) ? q : -1;
            float2 wv = w1[(lc >= 0) ? lc : 0];
            rn  = (lc >= 0) ? wv.x : 0.f;
            drm = (lc >= 0) ? wv.y : 0.f;
            dg = false;
        }
        // compute current tile from LDS
        const char* Bp = &sm[(i & 1) * 8192 + lane * 16];
        float16 a;
#pragma unroll
        for (int reg = 0; reg < 16; ++reg) a[reg] = 0.f;
#pragma unroll
        for (int ks = 0; ks < 8; ++ks) {
            short8 Bf = *(const short8*)(Bp + ks * 1024);
            a = __builtin_amdgcn_mfma_f32_32x32x16_bf16(Ah[ks], Bf, a, 0, 0, 0);
        }
        epi_tile(a, cb, lc, rn, drm, dg, half, ln, growbase, rlab, sS, sN);
        // commit staged tile to the other buffer, then one barrier
        if (more) {
            char* d = &sm[((i + 1) & 1) * 8192 + soff];
            *(short8*)d = st0;
            *(short8*)(d + 1024) = st1;
        }
        __syncthreads();
    }

    const int slice = isB2 ? cg : (NCG2 + t1);
#pragma unroll
    for (int reg = 0; reg < 16; ++reg) {
        float av = sS[reg], c = sN[reg];
#pragma unroll
        for (int off = 1; off < 32; off <<= 1) {
            av += __shfl_xor(av, off, 64);
            c  += __shfl_xor(c, off, 64);
        }
        if (ln == 0) {
            int ro = (reg & 3) + 8 * (reg >> 2) + 4 * half;
            int grow = growbase + ro;
            pS[(size_t)slice * BB + grow] = av;
            pN[(size_t)slice * BB + grow] = c;
        }
    }
}

// ---------------- reduce: 32 blocks; 8 threads/row sum the 141 slices + loss math ------
__global__ __launch_bounds__(256) void reduce_k(
    const int* __restrict__ labels,
    const float* __restrict__ cAf, const int* __restrict__ cBi,
    const float* __restrict__ pS, const float* __restrict__ pN,
    const float* __restrict__ supS, const float* __restrict__ supLi,
    float* __restrict__ partial) {
    const int g = blockIdx.x, t = threadIdx.x;
    const int rl = t >> 3, j = t & 7;
    const int row = g * 32 + rl;
    float S2 = 0.f, N2 = 0.f, S1 = 0.f, N1v = 0.f;
    for (int c = j; c < NCG2; c += 8) {
        S2 += pS[(size_t)c * BB + row];
        N2 += pN[(size_t)c * BB + row];
    }
    for (int c = NCG2 + j; c < NSL; c += 8) {
        S1  += pS[(size_t)c * BB + row];
        N1v += pN[(size_t)c * BB + row];
    }
#pragma unroll
    for (int off = 1; off < 8; off <<= 1) {
        S2 += __shfl_xor(S2, off, 64);  N2  += __shfl_xor(N2, off, 64);
        S1 += __shfl_xor(S1, off, 64);  N1v += __shfl_xor(N1v, off, 64);
    }
    float s = 0.f;
    if (j == 0) {
        int li = labels[row];
        S2 += supS[row];
        N2 *= INV_T; N1v *= INV_T;
        float sli = supLi[row];
        float cA = cAf[li];
        float msum2 = fmaf(ALPHA, cA - 1.f, 1.f);
        float loss2 = -(fmaf(ALPHA, N2, sli) / msum2 - INV_T - logf(S2 + EPSV));
        float loss1 = -(N1v / (float)cBi[li] - INV_T - logf(S1 + EPSV));
        s = loss1 + loss2;
    }
#pragma unroll
    for (int off = 1; off < 64; off <<= 1) s += __shfl_xor(s, off, 64);
    __shared__ float buf[4];
    if ((t & 63) == 0) buf[t >> 6] = s;
    __syncthreads();
    if (t == 0) partial[g] = (buf[0] + buf[1]) + (buf[2] + buf[3]);
}

// ---------------- final: one wave sums 32 block partials ----------------
__global__ __launch_bounds__(64) void final_k(const float* __restrict__ partial,
                                              float* __restrict__ out) {
    const int t = threadIdx.x;
    float s = (t < 32) ? partial[t] : 0.f;
#pragma unroll
    for (int off = 1; off < 64; off <<= 1) s += __shfl_xor(s, off, 64);
    if (t == 0) out[0] = s / (float)BB;   // single writer, plain store
}

extern "C" void kernel_launch(void* const* d_in, const int* in_sizes, int n_in,
                              void* d_out, int out_size, void* d_ws, size_t ws_size,
                              hipStream_t stream) {
    const float* feats   = (const float*)d_in[0];
    const float* sup     = (const float*)d_in[1];
    const float* centers = (const float*)d_in[2];
    const int*   labels  = (const int*)d_in[3];
    float* out = (float*)d_out;
    char*  wsb = (char*)d_ws;

    const size_t X2_BYTES = (size_t)NCB * 8192;         // 8,683,520
    unsigned short* X2 = (unsigned short*)wsb;
    char* base2 = wsb + X2_BYTES;
    int* cntP = (int*)base2;                            // 33*128 ints
    int* cntB = cntP + NHIST * 128;                     // 128 ints
    float2* wA = (float2*)(cntB + 128);                 // 128 float2 (8B-aligned)
    float2* w1 = wA + 128;                              // 128 float2
    float2* wS = w1 + 128;                              // 128 float2
    float*  cAf = (float*)(wS + 128);                   // 128 floats
    int*    cBi = (int*)(cAf + 128);                    // 128 ints
    float* pS = (float*)(cBi + 128);                    // 141*1024
    float* pN = pS + (size_t)NSL * BB;                  // 141*1024
    float* supS  = pN + (size_t)NSL * BB;               // 1024
    float* supLi = supS + BB;                           // 1024
    float* partial = supLi + BB;                        // 32

    // 5 nodes; every workspace word written before read (stream-ordered)
    prep_k<<<NCB + NHIST, 256, 0, stream>>>(feats, centers, labels, X2, cntP, cntB);
    tables_k<<<1, 128, 0, stream>>>(cntP, cntB, wA, w1, wS, cAf, cBi);
    gemm_k<<<18 * 64, 256, 0, stream>>>(X2, labels, wA, w1, wS, sup,
                                        pS, pN, supS, supLi);
    reduce_k<<<32, 256, 0, stream>>>(labels, cAf, cBi, pS, pN, supS, supLi, partial);
    final_k<<<1, 64, 0, stream>>>(partial, out);
}

// Round 4
// 121.476 us; speedup vs baseline: 1.2767x; 1.0367x over previous
//
#include <hip/hip_runtime.h>
#include <math.h>

#define KQ   32768
#define CC   100
#define BB   1024
#define DD   128
#define NTOT (BB + KQ)        // 33792
#define CB_CENT 1056
#define NCB  1060             // 32-row blocks in X2
#define NHIST 33              // histogram partial blocks
#define NCG2 132              // branch-2 col groups (8 cb each)
#define CG_SUP 141            // sup group id (after 9 branch-1 groups)
#define NSL  141              // partial-sum slices (132 b2 + 9 b1)

#define INV_T  14.285714285714286f
#define K2E    20.609929f     // INV_T * log2(e)
#define ALPHA  0.05f
#define EPSV   1e-12f

typedef __attribute__((ext_vector_type(8)))  short          short8;
typedef __attribute__((ext_vector_type(8)))  unsigned short ushort8;
typedef __attribute__((ext_vector_type(16))) float          float16;

__device__ __forceinline__ unsigned short f2bf_rne(float f) {
    unsigned int u = __float_as_uint(f);
    return (unsigned short)((u + 0x7FFFu + ((u >> 16) & 1u)) >> 16);
}

// X2 layout per 32-row block cb (8192 B): [ks 0..7][lane 0..63][16 B]
// element (row r, k): cb=r>>5, ks=k>>4, lane=(r&31)+32*((k>>3)&1), j=k&7
// == 32x32x16 MFMA A/B operand layout (verified R2-R15).
// HARD RULES: no device-scope fences/tickets in hot kernel (R13);
// never plain-store into a cross-block atomic accumulation target (R14);
// gemm_k VGPR must stay <= 128: never bound below that (R1 post-mortem:
// (64,4) capped VGPR at 64 -> 126 MB scratch spill, 1.3x regression).
// R2/R3 post-mortem: TLP and LDS-staging changes don't move gemm wall;
// R4 removes the per-tile serial labels->weights gather chain (hoisted).

// ---------------- prep: convert+tile (1 cb/block) + partial histograms ----------------
__global__ __launch_bounds__(256) void prep_k(const float* __restrict__ feats,
                                              const float* __restrict__ centers,
                                              const int* __restrict__ labels,
                                              unsigned short* __restrict__ X2,
                                              int* __restrict__ cntP,
                                              int* __restrict__ cntB) {
    const int b = blockIdx.x, t = threadIdx.x;
    if (b >= NCB) {  // histogram partials: each block owns its own 128-int slice
        const int h = b - NCB;
        __shared__ int hA[CC], hB[CC];
        if (t < CC) { hA[t] = 0; hB[t] = 0; }
        __syncthreads();
        const int base = h * 1024;
#pragma unroll
        for (int q = 0; q < 4; ++q) {
            int l = labels[base + q * 256 + t];
            atomicAdd(&hA[l], 1);
            if (h == 0) atomicAdd(&hB[l], 1);   // batch rows are exactly block 0's range
        }
        __syncthreads();
        if (t < 128) {
            cntP[h * 128 + t] = (t < CC) ? hA[t] : 0;
            if (h == 0) cntB[t] = (t < CC) ? hB[t] : 0;
        }
        return;
    }
    __shared__ unsigned short sm[8 * 66 * 8];   // stride-66 slots
    const int cb = b;
    const int rl = t >> 3, c8 = t & 7;
    const int r = cb * 32 + rl;
    const float* src;
    if (r < NTOT)            src = &feats[(size_t)r * DD];
    else if (r < NTOT + CC)  src = &centers[(size_t)(r - NTOT) * DD];
    else                     src = nullptr;
#pragma unroll
    for (int s = 0; s < 2; ++s) {
        const int c8p = c8 + 8 * s;
        float v[8];
        if (src) {
            const float4* p = (const float4*)(src + c8p * 8);
            float4 q0 = p[0], q1 = p[1];
            v[0]=q0.x; v[1]=q0.y; v[2]=q0.z; v[3]=q0.w;
            v[4]=q1.x; v[5]=q1.y; v[6]=q1.z; v[7]=q1.w;
        } else {
#pragma unroll
            for (int j = 0; j < 8; ++j) v[j] = 0.f;
        }
        ushort8 H;
#pragma unroll
        for (int m = 0; m < 8; ++m) H[m] = f2bf_rne(v[m]);
        const int ks = c8p >> 1, lh = c8p & 1;
        *(ushort8*)&sm[(ks * 66 + rl + 32 * lh) * 8] = H;
    }
    __syncthreads();
    ushort8* dst = (ushort8*)((char*)X2 + (size_t)cb * 8192);
#pragma unroll
    for (int j = 0; j < 2; ++j) {
        const int idx = j * 256 + t;
        const int ks = idx >> 6, ln2 = idx & 63;
        dst[idx] = *(const ushort8*)&sm[(ks * 66 + ln2) * 8];
    }
}

// ---------------- tables: one tiny block; sums hist partials, emits weight tables ------
__global__ __launch_bounds__(128) void tables_k(
    const int* __restrict__ cntP, const int* __restrict__ cntB,
    float2* __restrict__ wA, float2* __restrict__ w1, float2* __restrict__ wS,
    float* __restrict__ cAf, int* __restrict__ cBi) {
    const int t = threadIdx.x;   // 0..127
    int s = 0;
#pragma unroll
    for (int h = 0; h < NHIST; ++h) s += cntP[h * 128 + t];
    float cf = (float)s;
    float rn = (s > 0) ? __builtin_amdgcn_rcpf(cf) : 0.f;
    float dr = (s > 0) ? (__builtin_amdgcn_rcpf(cf - ALPHA) - rn) : 0.f;
    wA[t] = make_float2(rn, dr);
    wS[t] = make_float2(__builtin_amdgcn_rcpf(cf),
                        __builtin_amdgcn_rcpf(fmaxf(cf - 1.f, 1.f)));
    int sb = cntB[t];
    float c1 = (float)(sb + 1);
    float r1 = __builtin_amdgcn_rcpf(c1);
    w1[t] = make_float2(r1, __builtin_amdgcn_rcpf(fmaxf(c1 - 1.f, 1.f)) - r1);
    cAf[t] = cf;
    cBi[t] = sb;
}

// ---------------- epilogue for one 32x32 tile ----------------
__device__ __forceinline__ void epi_tile(
    const float16& acc, int cb, int lc, float rn, float drm, bool checkDiag,
    int half, int ln, int growbase, const int* rlab, float* sS, float* sN)
{
    const int ccol = cb * 32 + ln;
#pragma unroll
    for (int reg = 0; reg < 16; ++reg) {
        int ro = (reg & 3) + 8 * (reg >> 2) + 4 * half;
        float a  = acc[reg];
        float mf = (lc == rlab[reg]) ? 1.f : 0.f;
        float wgt = fmaf(mf, drm, rn);
        if (checkDiag) {                 // wave-uniform
            bool d = (ccol == growbase + ro);
            wgt = d ? 0.f : wgt;
            mf  = d ? 0.f : mf;
        }
        float e = exp2f(fmaf(a, K2E, -K2E));
        sS[reg] = fmaf(e, wgt, sS[reg]);
        sN[reg] = fmaf(mf, a, sN[reg]);  // un-scaled dot; *INV_T at finalize
    }
}

// ---------------- fused GEMM (b2 + b1) + sup-sums; 4-wave LDS dbuf, hoisted gathers ----
// grid 1152 = 18 chunk * 8 rgrp * 8 xcd; cg = chunk*8 + xcd.
// cg<132: branch2 (8 cb). 132..140: branch1 (4 cb). 141: sup sums. 142/143: idle.
// All per-tile labels/weight gathers are batched in the prologue (independent,
// pipelined); weight lookups hit an LDS copy of the 1KB tables. Tile loop body
// is pure ds_read -> MFMA -> register epilogue -> staged write.
__global__ __launch_bounds__(256, 2) void gemm_k(
    const unsigned short* __restrict__ X2, const int* __restrict__ labels,
    const float2* __restrict__ wA, const float2* __restrict__ w1,
    const float2* __restrict__ wS, const float* __restrict__ sup,
    float* __restrict__ pS, float* __restrict__ pN,
    float* __restrict__ supS, float* __restrict__ supLi) {
    const int b = blockIdx.x;
    const int xcd = b & 7, rgrp = (b >> 3) & 7, chunk = b >> 6;
    const int cg = chunk * 8 + xcd;
    if (cg > CG_SUP) return;

    const int tid = threadIdx.x;
    const int w = tid >> 6, lane = tid & 63;
    const int half = lane >> 5, ln = lane & 31;
    const int rb = rgrp * 4 + w;
    const char* Xb = (const char*)X2;

    if (cg == CG_SUP) {  // sup-logits exp-sums: wave owns rows rb*32..rb*32+31
        const int c0 = lane, c1 = lane + 64;
        float2 t0 = wS[c0];
        float rA0 = t0.x, rAm0 = t0.y;
        float rA1 = 0.f, rAm1 = 0.f;
        if (lane < 36) { float2 t1v = wS[c1]; rA1 = t1v.x; rAm1 = t1v.y; }
        for (int rr = 0; rr < 32; ++rr) {
            int row = rb * 32 + rr;
            int li = labels[row];
            const float* srow = &sup[(size_t)row * CC];
            float v0 = srow[c0];
            float s = __expf(v0 - INV_T) * ((c0 == li) ? rAm0 : rA0);
            float liv = (c0 == li) ? v0 : 0.f;
            if (lane < 36) {
                float v1 = srow[c1];
                s += __expf(v1 - INV_T) * ((c1 == li) ? rAm1 : rA1);
                liv += (c1 == li) ? v1 : 0.f;
            }
#pragma unroll
            for (int off = 1; off < 64; off <<= 1) {
                s += __shfl_xor(s, off, 64);
                liv += __shfl_xor(liv, off, 64);
            }
            if (lane == 0) { supS[row] = s; supLi[row] = liv; }
        }
        return;
    }

    __shared__ char sm[2 * 8192];       // double-buffered B tile (MFMA operand order)
    __shared__ float2 wT[128];          // LDS copy of the relevant weight table

    const bool isB2 = (cg < NCG2);
    const int t1 = cg - NCG2;
    const bool isBatch = isB2 || (t1 < 8);
    const int NIT = isB2 ? 8 : 4;
    const int cb0 = isB2 ? cg * 8 : (t1 < 8 ? t1 * 4 : CB_CENT);

    if (tid < 128) wT[tid] = isB2 ? wA[tid] : w1[tid];
    __syncthreads();

    // ---- hoisted per-tile column labels (8 independent global gathers) ----
    int lcv[8];
#pragma unroll
    for (int i = 0; i < 8; ++i) {
        if (i < NIT) {
            const int cb = cb0 + i;
            if (isBatch) {
                lcv[i] = labels[cb * 32 + ln];
            } else {
                int q = cb * 32 + ln - NTOT;
                lcv[i] = (q < CC) ? q : -1;
            }
        } else lcv[i] = -1;
    }

    const int growbase = rb * 32;
    short8 Ah[8];
    {
        size_t abase = (size_t)rb * 8192 + (size_t)lane * 16;
#pragma unroll
        for (int ks = 0; ks < 8; ++ks)
            Ah[ks] = *(const short8*)(Xb + abase + (size_t)ks * 1024);
    }
    int rlab[16];
#pragma unroll
    for (int reg = 0; reg < 16; ++reg) {
        int ro = (reg & 3) + 8 * (reg >> 2) + 4 * half;
        rlab[reg] = labels[growbase + ro];
    }

    // ---- hoisted per-tile weights from LDS table ----
    float rnv[8], drv[8];
#pragma unroll
    for (int i = 0; i < 8; ++i) {
        if (i < NIT) {
            int lc = lcv[i];
            float2 wv = wT[(lc >= 0) ? lc : 0];
            rnv[i] = (lc >= 0) ? wv.x : 0.f;
            drv[i] = (lc >= 0) ? wv.y : 0.f;
        } else { rnv[i] = 0.f; drv[i] = 0.f; }
    }

    float sS[16], sN[16];
#pragma unroll
    for (int reg = 0; reg < 16; ++reg) { sS[reg] = 0.f; sN[reg] = 0.f; }

    // per-wave staging offsets: wave w owns ks-slices 2w, 2w+1 (1 KB each)
    const int soff = (w * 2) * 1024 + lane * 16;

    // prologue: stage cb0 into buffer 0
    {
        const char* src = Xb + (size_t)cb0 * 8192 + soff;
        short8 s0 = *(const short8*)src;
        short8 s1 = *(const short8*)(src + 1024);
        *(short8*)&sm[soff] = s0;
        *(short8*)&sm[soff + 1024] = s1;
    }
    __syncthreads();

    for (int i = 0; i < NIT; ++i) {
        const int cb = cb0 + i;
        // issue next tile's global loads early (latency hides under compute)
        short8 st0, st1;
        const bool more = (i + 1 < NIT);
        if (more) {
            const char* src = Xb + (size_t)(cb + 1) * 8192 + soff;
            st0 = *(const short8*)src;
            st1 = *(const short8*)(src + 1024);
        }
        // compute current tile from LDS
        const char* Bp = &sm[(i & 1) * 8192 + lane * 16];
        float16 a;
#pragma unroll
        for (int reg = 0; reg < 16; ++reg) a[reg] = 0.f;
#pragma unroll
        for (int ks = 0; ks < 8; ++ks) {
            short8 Bf = *(const short8*)(Bp + ks * 1024);
            a = __builtin_amdgcn_mfma_f32_32x32x16_bf16(Ah[ks], Bf, a, 0, 0, 0);
        }
        epi_tile(a, cb, lcv[i], rnv[i], drv[i], isBatch && (cb == rb),
                 half, ln, growbase, rlab, sS, sN);
        // commit staged tile to the other buffer, then one barrier
        if (more) {
            char* d = &sm[((i + 1) & 1) * 8192 + soff];
            *(short8*)d = st0;
            *(short8*)(d + 1024) = st1;
        }
        __syncthreads();
    }

    const int slice = isB2 ? cg : (NCG2 + t1);
#pragma unroll
    for (int reg = 0; reg < 16; ++reg) {
        float av = sS[reg], c = sN[reg];
#pragma unroll
        for (int off = 1; off < 32; off <<= 1) {
            av += __shfl_xor(av, off, 64);
            c  += __shfl_xor(c, off, 64);
        }
        if (ln == 0) {
            int ro = (reg & 3) + 8 * (reg >> 2) + 4 * half;
            int grow = growbase + ro;
            pS[(size_t)slice * BB + grow] = av;
            pN[(size_t)slice * BB + grow] = c;
        }
    }
}

// ---------------- reduce: 128 blocks; 32 threads/row sum the 141 slices + loss math ----
__global__ __launch_bounds__(256) void reduce_k(
    const int* __restrict__ labels,
    const float* __restrict__ cAf, const int* __restrict__ cBi,
    const float* __restrict__ pS, const float* __restrict__ pN,
    const float* __restrict__ supS, const float* __restrict__ supLi,
    float* __restrict__ partial) {
    const int g = blockIdx.x, t = threadIdx.x;
    const int rl = t >> 5, j = t & 31;        // 8 rows/block, 32 lanes/row
    const int row = g * 8 + rl;
    float S2 = 0.f, N2 = 0.f, S1 = 0.f, N1v = 0.f;
    for (int c = j; c < NCG2; c += 32) {
        S2 += pS[(size_t)c * BB + row];
        N2 += pN[(size_t)c * BB + row];
    }
    if (NCG2 + j < NSL) {
        S1  += pS[(size_t)(NCG2 + j) * BB + row];
        N1v += pN[(size_t)(NCG2 + j) * BB + row];
    }
#pragma unroll
    for (int off = 1; off < 32; off <<= 1) {
        S2 += __shfl_xor(S2, off, 64);  N2  += __shfl_xor(N2, off, 64);
        S1 += __shfl_xor(S1, off, 64);  N1v += __shfl_xor(N1v, off, 64);
    }
    float s = 0.f;
    if (j == 0) {
        int li = labels[row];
        S2 += supS[row];
        N2 *= INV_T; N1v *= INV_T;
        float sli = supLi[row];
        float cA = cAf[li];
        float msum2 = fmaf(ALPHA, cA - 1.f, 1.f);
        float loss2 = -(fmaf(ALPHA, N2, sli) / msum2 - INV_T - logf(S2 + EPSV));
        float loss1 = -(N1v / (float)cBi[li] - INV_T - logf(S1 + EPSV));
        s = loss1 + loss2;
    }
#pragma unroll
    for (int off = 1; off < 64; off <<= 1) s += __shfl_xor(s, off, 64);
    __shared__ float buf[4];
    if ((t & 63) == 0) buf[t >> 6] = s;
    __syncthreads();
    if (t == 0) partial[g] = (buf[0] + buf[1]) + (buf[2] + buf[3]);
}

// ---------------- final: one wave sums 128 block partials ----------------
__global__ __launch_bounds__(64) void final_k(const float* __restrict__ partial,
                                              float* __restrict__ out) {
    const int t = threadIdx.x;
    float s = partial[t] + partial[t + 64];
#pragma unroll
    for (int off = 1; off < 64; off <<= 1) s += __shfl_xor(s, off, 64);
    if (t == 0) out[0] = s / (float)BB;   // single writer, plain store
}

extern "C" void kernel_launch(void* const* d_in, const int* in_sizes, int n_in,
                              void* d_out, int out_size, void* d_ws, size_t ws_size,
                              hipStream_t stream) {
    const float* feats   = (const float*)d_in[0];
    const float* sup     = (const float*)d_in[1];
    const float* centers = (const float*)d_in[2];
    const int*   labels  = (const int*)d_in[3];
    float* out = (float*)d_out;
    char*  wsb = (char*)d_ws;

    const size_t X2_BYTES = (size_t)NCB * 8192;         // 8,683,520
    unsigned short* X2 = (unsigned short*)wsb;
    char* base2 = wsb + X2_BYTES;
    int* cntP = (int*)base2;                            // 33*128 ints
    int* cntB = cntP + NHIST * 128;                     // 128 ints
    float2* wA = (float2*)(cntB + 128);                 // 128 float2 (8B-aligned)
    float2* w1 = wA + 128;                              // 128 float2
    float2* wS = w1 + 128;                              // 128 float2
    float*  cAf = (float*)(wS + 128);                   // 128 floats
    int*    cBi = (int*)(cAf + 128);                    // 128 ints
    float* pS = (float*)(cBi + 128);                    // 141*1024
    float* pN = pS + (size_t)NSL * BB;                  // 141*1024
    float* supS  = pN + (size_t)NSL * BB;               // 1024
    float* supLi = supS + BB;                           // 1024
    float* partial = supLi + BB;                        // 128

    // 5 nodes; every workspace word written before read (stream-ordered)
    prep_k<<<NCB + NHIST, 256, 0, stream>>>(feats, centers, labels, X2, cntP, cntB);
    tables_k<<<1, 128, 0, stream>>>(cntP, cntB, wA, w1, wS, cAf, cBi);
    gemm_k<<<18 * 64, 256, 0, stream>>>(X2, labels, wA, w1, wS, sup,
                                        pS, pN, supS, supLi);
    reduce_k<<<128, 256, 0, stream>>>(labels, cAf, cBi, pS, pN, supS, supLi, partial);
    final_k<<<1, 64, 0, stream>>>(partial, out);
}